// Round 28
// baseline (23.442 us; speedup 1.0000x reference)
//
#include <hip/hip_runtime.h>

// Volume rendering composite (cumprod along chunk-row axis, per-column).
//
// R28: second CU-spread doubling, coalescing preserved. R27 (CG=32,
// 32 blocks): 18.9us, confirming per-CU-BW model (~38 GB/s/CU). R26's
// failure pinpointed the cliff: runs < 64 B half-fill sectors. CG=16
// keeps each run = 16 floats = one FULL 64-B sector; a wave covers
// 4 slots x 16 cols = 4 full sectors/instruction. 64 blocks (8 chunks x
// 8 col-groups) on 64 CUs; WIN=128 rows (64 slots x RPS=2) -> walked
// bytes unchanged (~640 live rows/chunk). Register-resident strips; ONE
// barrier per window (sig double-buffered); per-column Tcur register
// identical across waves -> block-uniform __all exit. Early exit exact
// to 8e-12 via telescoping (|f|<=1, z<8) vs 0.16 threshold; adversarial
// data walks more windows (exact).
// ONE dispatch, no workspace, no atomics, no fences, no memsets.

#define P 128
#define FARD 1.0e10f
#define EPS 1.0e-12f
#define CG 16             // columns per block (= one 64-B sector per run)
#define SLOTS 64          // row-slots per window
#define RPS 2             // rows per slot
#define WIN (SLOTS * RPS) // 128 rows per window

__global__ __launch_bounds__(1024) void render_kernel(
    const float* __restrict__ density,
    const float* __restrict__ feature,
    const float* __restrict__ depth,
    float* __restrict__ out,
    int chunk, int n_chunks)
{
    __shared__ float sig[2][SLOTS][CG];           // 8 KB, double-buffered
    __shared__ float acc[SLOTS][CG][4];           // 16 KB
    const int tid = threadIdx.x;
    const int colg = tid & (CG - 1);              // 0..15
    const int slot = tid >> 4;                    // 0..63
    const int c = blockIdx.x >> 3;                // chunk
    const int q = blockIdx.x & 7;                 // column group
    const int col = q * CG + colg;
    const bool far  = (col == P - 1);
    const bool edge = (colg == CG - 1);
    const long long cbase = (long long)c * chunk;

    float Tcur = 1.f;                             // per-column, wave-uniform
    float fa0 = 0.f, fa1 = 0.f, fa2 = 0.f, da = 0.f;

    const int nwin = chunk / WIN;                 // 64
    for (int it = 0; it < nwin; ++it) {
        const long long r0 = cbase + (long long)it * WIN + slot * RPS;

        // Batch-load the slot's rows: d, z, feature (latency overlapped).
        float dv[RPS], zv[RPS], ev[RPS], f0[RPS], f1[RPS], f2[RPS];
        #pragma unroll
        for (int r = 0; r < RPS; ++r) {
            const long long h = (r0 + r) * P + col;
            dv[r] = density[h];
            zv[r] = depth[h];
            float3 fv = ((const float3*)feature)[h];
            f0[r] = fv.x; f1[r] = fv.y; f2[r] = fv.z;
        }
        // Slot sum of s; e in registers.
        float sg = 0.f;
        #pragma unroll
        for (int r = 0; r < RPS; ++r) {
            float zn = __shfl_down(zv[r], 1);     // next col, same row
            if (edge) {                           // group-boundary patch
                zn = far ? zv[r] : depth[(r0 + r) * P + col + 1];
            }
            float s = dv[r] * (far ? FARD : (zn - zv[r]));
            ev[r] = __expf(-s);
            sg += s;
        }
        sig[it & 1][slot][colg] = sg;
        __syncthreads();                          // the window's ONE barrier

        // Stitch: exclusive prefix over 64 slots + window total.
        float pre = 0.f, total = 0.f;
        #pragma unroll
        for (int k = 0; k < SLOTS; ++k) {
            float v = sig[it & 1][k][colg];
            pre += (k < slot) ? v : 0.f;
            total += v;
        }
        float Trun = Tcur * __expf(-pre);         // T at slot start

        // Composite: pure register compute.
        #pragma unroll
        for (int r = 0; r < RPS; ++r) {
            float Tn = Trun * ev[r];              // running cumprod (ref)
            float wt = Trun - Tn;                 // T_i * (1 - temp_i)
            Trun = Tn;
            fa0 += wt * f0[r]; fa1 += wt * f1[r]; fa2 += wt * f2[r];
            da  += wt * zv[r];
        }

        Tcur *= __expf(-total);                   // window-end T (per col)
        if (__all(Tcur < EPS)) break;             // telescoping bound
    }

    // Reduce the 64 slot-accumulators per column (fixed order); write out.
    acc[slot][colg][0] = fa0; acc[slot][colg][1] = fa1;
    acc[slot][colg][2] = fa2; acc[slot][colg][3] = da;
    __syncthreads();
    if (tid < CG * 4) {                           // 64 outputs per block
        const int comp = tid >> 4, col2 = tid & (CG - 1);
        float s = 0.f;
        #pragma unroll
        for (int k = 0; k < SLOTS; ++k) s += acc[k][col2][comp];
        const int gcol = q * CG + col2;
        if (comp < 3) out[((long long)c * P + gcol) * 3 + comp] = s;
        else out[(long long)n_chunks * P * 3 + (long long)c * P + gcol] = s;
    }
}

extern "C" void kernel_launch(void* const* d_in, const int* in_sizes, int n_in,
                              void* d_out, int out_size, void* d_ws, size_t ws_size,
                              hipStream_t stream)
{
    const float* density = (const float*)d_in[0];
    const float* feature = (const float*)d_in[1];
    const float* depth   = (const float*)d_in[2];
    float* out = (float*)d_out;

    const int B = in_sizes[0] / P;        // 65536
    const int chunk = 8192;               // matches setup_inputs() chunk_size
    const int n_chunks = B / chunk;       // 8

    render_kernel<<<n_chunks * 8, 1024, 0, stream>>>(density, feature, depth,
                                                     out, chunk, n_chunks);
}

// Round 29
// 14.716 us; speedup vs baseline: 1.5929x; 1.5929x over previous
//
#include <hip/hip_runtime.h>

// Volume rendering composite (cumprod along chunk-row axis, per-column).
//
// R29: XCD-paired half-line blocks. Coalescing quantum is the 128-B L2
// line (R26: 32-B runs 2x-fetch; R28: 64-B runs 2x-fetch across XCDs;
// R27: 128-B runs = best, 18.9us but capped at 32 blocks). Here 64 blocks
// of 512 thr; the two blocks covering the two 64-B halves of each line
// are placed at dispatch indices b and b+32 (b ≡ b+32 mod 8 -> same XCD
// under the observed round-robin XCD mapping; heuristic, perf-only).
// Each line is HBM-fetched once, partner hits that XCD's L2; per-XCD
// walked set 1.6 MB << 4 MB L2 so skewed partners still hit.
// Block: 32 slots x 16 cols, RPS=4 (R27's per-lane ILP), WIN=128 rows;
// register-resident strips; ONE barrier per window (sig double-buffered);
// per-column Tcur register identical across waves -> block-uniform __all
// exit. Early exit exact to 8e-12 via telescoping (|f|<=1, z<8) vs 0.16
// threshold; adversarial data walks more windows (exact).
// ONE dispatch, no workspace, no atomics, no fences, no memsets.

#define P 128
#define FARD 1.0e10f
#define EPS 1.0e-12f
#define CG 16             // columns per block (half a 128-B line)
#define SLOTS 32          // row-slots per window
#define RPS 4             // rows per slot
#define WIN (SLOTS * RPS) // 128 rows per window

__global__ __launch_bounds__(512) void render_kernel(
    const float* __restrict__ density,
    const float* __restrict__ feature,
    const float* __restrict__ depth,
    float* __restrict__ out,
    int chunk, int n_chunks)
{
    __shared__ float sig[2][SLOTS][CG];           // 4 KB, double-buffered
    __shared__ float acc[SLOTS][CG][4];           // 8 KB
    const int tid = threadIdx.x;
    const int colg = tid & (CG - 1);              // 0..15
    const int slot = tid >> 4;                    // 0..31
    // Pairing: blocks b and b+32 share (c,q) and differ in half h ->
    // same XCD under round-robin (b mod 8 == (b+32) mod 8).
    const int pair = blockIdx.x & 31;             // 0..31 -> (c, q)
    const int h    = blockIdx.x >> 5;             // 0/1: which line half
    const int c = pair >> 2;                      // chunk
    const int q = pair & 3;                       // column quarter
    const int col = q * 32 + h * CG + colg;
    const bool far  = (col == P - 1);
    const bool edge = (colg == CG - 1);
    const long long cbase = (long long)c * chunk;

    float Tcur = 1.f;                             // per-column, wave-uniform
    float fa0 = 0.f, fa1 = 0.f, fa2 = 0.f, da = 0.f;

    const int nwin = chunk / WIN;                 // 64
    for (int it = 0; it < nwin; ++it) {
        const long long r0 = cbase + (long long)it * WIN + slot * RPS;

        // Batch-load the slot's rows: d, z, feature (latency overlapped).
        float dv[RPS], zv[RPS], ev[RPS], f0[RPS], f1[RPS], f2[RPS];
        #pragma unroll
        for (int r = 0; r < RPS; ++r) {
            const long long hh = (r0 + r) * P + col;
            dv[r] = density[hh];
            zv[r] = depth[hh];
            float3 fv = ((const float3*)feature)[hh];
            f0[r] = fv.x; f1[r] = fv.y; f2[r] = fv.z;
        }
        // Slot sum of s; e in registers.
        float sg = 0.f;
        #pragma unroll
        for (int r = 0; r < RPS; ++r) {
            float zn = __shfl_down(zv[r], 1);     // next col, same row
            if (edge) {                           // group-boundary patch
                zn = far ? zv[r] : depth[(r0 + r) * P + col + 1];
            }
            float s = dv[r] * (far ? FARD : (zn - zv[r]));
            ev[r] = __expf(-s);
            sg += s;
        }
        sig[it & 1][slot][colg] = sg;
        __syncthreads();                          // the window's ONE barrier

        // Stitch: exclusive prefix over 32 slots + window total.
        float pre = 0.f, total = 0.f;
        #pragma unroll
        for (int k = 0; k < SLOTS; ++k) {
            float v = sig[it & 1][k][colg];
            pre += (k < slot) ? v : 0.f;
            total += v;
        }
        float Trun = Tcur * __expf(-pre);         // T at slot start

        // Composite: pure register compute.
        #pragma unroll
        for (int r = 0; r < RPS; ++r) {
            float Tn = Trun * ev[r];              // running cumprod (ref)
            float wt = Trun - Tn;                 // T_i * (1 - temp_i)
            Trun = Tn;
            fa0 += wt * f0[r]; fa1 += wt * f1[r]; fa2 += wt * f2[r];
            da  += wt * zv[r];
        }

        Tcur *= __expf(-total);                   // window-end T (per col)
        if (__all(Tcur < EPS)) break;             // telescoping bound
    }

    // Reduce the 32 slot-accumulators per column (fixed order); write out.
    acc[slot][colg][0] = fa0; acc[slot][colg][1] = fa1;
    acc[slot][colg][2] = fa2; acc[slot][colg][3] = da;
    __syncthreads();
    if (tid < CG * 4) {                           // 64 outputs per block
        const int comp = tid >> 4, col2 = tid & (CG - 1);
        float s = 0.f;
        #pragma unroll
        for (int k = 0; k < SLOTS; ++k) s += acc[k][col2][comp];
        const int gcol = q * 32 + h * CG + col2;
        if (comp < 3) out[((long long)c * P + gcol) * 3 + comp] = s;
        else out[(long long)n_chunks * P * 3 + (long long)c * P + gcol] = s;
    }
}

extern "C" void kernel_launch(void* const* d_in, const int* in_sizes, int n_in,
                              void* d_out, int out_size, void* d_ws, size_t ws_size,
                              hipStream_t stream)
{
    const float* density = (const float*)d_in[0];
    const float* feature = (const float*)d_in[1];
    const float* depth   = (const float*)d_in[2];
    float* out = (float*)d_out;

    const int B = in_sizes[0] / P;        // 65536
    const int chunk = 8192;               // matches setup_inputs() chunk_size
    const int n_chunks = B / chunk;       // 8

    render_kernel<<<64, 512, 0, stream>>>(density, feature, depth,
                                          out, chunk, n_chunks);
}